// Round 6
// baseline (886.178 us; speedup 1.0000x reference)
//
#include <hip/hip_runtime.h>
#include <stdint.h>

// HashEncoder (Instant-NGP / HashNeRF): 1M points, 16 levels, 2 feats, 2^19 table.
// R9: XCD-partitioned level pairs. R8's fused all-levels loop measured FETCH=2.0GB
// (vs ~76MB useful): every XCD swept every 4MB table and resident-block drift put
// ~4 tables hot per 4MiB XCD-L2 -> thrash. New structure: blockIdx.x & 7 selects a
// level PAIR; consecutive blocks round-robin across the 8 XCDs, so each XCD owns
// exactly 2 tables (<=8MB working set) for the whole kernel and each table is
// fetched by one XCD only. Thread = 1 point x 2 levels -> one aligned float4
// store (16B = half a 32B HBM sector, <=2x write amp; no ws round-trip).
// x loads are non-temporal so the streamed 12MB/XCD doesn't evict the table.
// Predicted: FETCH 2.0GB -> 0.25-0.35GB, kernel 615 -> ~300-380us.
// If FETCH stays ~2GB the XCD round-robin assumption is wrong -> fall back to
// cooperative grid-barrier level lockstep next.

static constexpr int NP = 1048576;
static constexpr int NL = 16;
static constexpr int TPB = 256;
static constexpr uint32_t HMASK = (1u << 19) - 1u;

typedef float f32x4 __attribute__((ext_vector_type(4)));

// res_i = floor(16 * b^i), b = f32(exp((ln512-ln16)/15)) = 1.2599210739135742
// Verified: absmax 2.4e-7 vs reference (R8 run).
__constant__ float c_res[NL] = {16.f, 20.f, 25.f, 32.f, 40.f, 50.f, 64.f, 80.f,
                                101.f, 128.f, 161.f, 203.f, 256.f, 322.f, 406.f, 512.f};

__device__ __forceinline__ float2 enc_one(
    float x0, float x1, float x2,
    float b0, float b1, float b2,
    float B0, float B1, float B2,
    const float2* __restrict__ tab, float res, float gate)
{
    // index path must be bit-exact vs numpy f32: sub/div/floor only
    float g0 = (B0 - b0) / res;
    float g1 = (B1 - b1) / res;
    float g2 = (B2 - b2) / res;
    float xc0 = fminf(fmaxf(x0, b0), B0);
    float xc1 = fminf(fmaxf(x1, b1), B1);
    float xc2 = fminf(fmaxf(x2, b2), B2);
    float f0 = floorf((xc0 - b0) / g0);
    float f1 = floorf((xc1 - b1) / g1);
    float f2 = floorf((xc2 - b2) / g2);
    // interpolation weights use RAW x (per reference)
    float v0 = f0 * g0 + b0;
    float v1 = f1 * g1 + b1;
    float v2 = f2 * g2 + b2;
    float w0 = (x0 - v0) / ((v0 + g0) - v0);
    float w1 = (x1 - v1) / ((v1 + g1) - v1);
    float w2 = (x2 - v2) / ((v2 + g2) - v2);

    uint32_t u0 = (uint32_t)(int)f0;
    uint32_t u1 = (uint32_t)(int)f1;
    uint32_t u2 = (uint32_t)(int)f2;
    uint32_t ya = u1 * 2654435761u, yb = (u1 + 1u) * 2654435761u;
    uint32_t za = u2 * 805459861u,  zb = (u2 + 1u) * 805459861u;
    uint32_t xa = u0, xb = u0 + 1u;

    // corner index = i*4 + j*2 + k (i on x, j on y, k on z)
    float2 e000 = tab[(xa ^ ya ^ za) & HMASK];
    float2 e001 = tab[(xa ^ ya ^ zb) & HMASK];
    float2 e010 = tab[(xa ^ yb ^ za) & HMASK];
    float2 e011 = tab[(xa ^ yb ^ zb) & HMASK];
    float2 e100 = tab[(xb ^ ya ^ za) & HMASK];
    float2 e101 = tab[(xb ^ ya ^ zb) & HMASK];
    float2 e110 = tab[(xb ^ yb ^ za) & HMASK];
    float2 e111 = tab[(xb ^ yb ^ zb) & HMASK];

    float s0 = 1.f - w0, s1 = 1.f - w1, s2 = 1.f - w2;
    float cx00x = e000.x * s0 + e100.x * w0, cx00y = e000.y * s0 + e100.y * w0;
    float cx01x = e001.x * s0 + e101.x * w0, cx01y = e001.y * s0 + e101.y * w0;
    float cx10x = e010.x * s0 + e110.x * w0, cx10y = e010.y * s0 + e110.y * w0;
    float cx11x = e011.x * s0 + e111.x * w0, cx11y = e011.y * s0 + e111.y * w0;
    float c0x = cx00x * s1 + cx10x * w1, c0y = cx00y * s1 + cx10y * w1;
    float c1x = cx01x * s1 + cx11x * w1, c1y = cx01y * s1 + cx11y * w1;
    float ox = c0x * s2 + c1x * w2;
    float oy = c0y * s2 + c1y * w2;
    return make_float2(ox * gate, oy * gate);
}

// Thread = (point, level-pair). lp = blockIdx.x & 7 -> XCD id (round-robin
// dispatch), so XCD k only ever touches tables 2k and 2k+1.
__global__ __launch_bounds__(TPB) void k_enc_pair(
    const float* __restrict__ x, const float* __restrict__ emb,
    const float* __restrict__ lw, const float* __restrict__ bmin,
    const float* __restrict__ bmax, f32x4* __restrict__ out)
{
    int b  = blockIdx.x;
    int lp = b & 7;            // level pair / XCD slot
    int pb = b >> 3;           // point block 0..4095
    int p  = pb * TPB + (int)threadIdx.x;

    // streamed inputs: non-temporal so they don't evict the resident table
    float x0 = __builtin_nontemporal_load(x + 3 * p + 0);
    float x1 = __builtin_nontemporal_load(x + 3 * p + 1);
    float x2 = __builtin_nontemporal_load(x + 3 * p + 2);
    float b0 = bmin[0], b1 = bmin[1], b2 = bmin[2];
    float B0 = bmax[0], B1 = bmax[1], B2 = bmax[2];

    int l0 = 2 * lp, l1 = 2 * lp + 1;
    float res0 = c_res[l0], res1 = c_res[l1];
    float gate0 = 1.0f / (1.0f + expf(-lw[l0]));
    float gate1 = 1.0f / (1.0f + expf(-lw[l1]));
    const float2* tab0 = (const float2*)(emb + ((size_t)l0 << 20));
    const float2* tab1 = (const float2*)(emb + ((size_t)l1 << 20));

    float2 r0 = enc_one(x0, x1, x2, b0, b1, b2, B0, B1, B2, tab0, res0, gate0);
    float2 r1 = enc_one(x0, x1, x2, b0, b1, b2, B0, B1, B2, tab1, res1, gate1);

    // out floats 32p + 4*lp .. +3 = levels (2lp, 2lp+1) feats — aligned float4
    f32x4 v = {r0.x, r0.y, r1.x, r1.y};
    __builtin_nontemporal_store(v, &out[(size_t)p * 8 + lp]);
}

extern "C" void kernel_launch(void* const* d_in, const int* in_sizes, int n_in,
                              void* d_out, int out_size, void* d_ws, size_t ws_size,
                              hipStream_t stream) {
    const float* x    = (const float*)d_in[0];
    const float* emb  = (const float*)d_in[1];
    const float* lw   = (const float*)d_in[2];
    const float* bmin = (const float*)d_in[3];
    const float* bmax = (const float*)d_in[4];
    (void)d_ws; (void)ws_size;

    // 8 level-pairs x 4096 point-blocks; consecutive blocks -> consecutive XCDs
    k_enc_pair<<<dim3((NP / TPB) * 8), TPB, 0, stream>>>(
        x, emb, lw, bmin, bmax, (f32x4*)d_out);
}

// Round 7
// 707.488 us; speedup vs baseline: 1.2526x; 1.2526x over previous
//
#include <hip/hip_runtime.h>
#include <stdint.h>

// HashEncoder (Instant-NGP / HashNeRF): 1M points, 16 levels, 2 feats, 2^19 table.
// R10: per-level sequential launches (lockstep by dispatch).
// Evidence so far: R8 fused-all-levels -> FETCH 2.0GB (drift: many tables hot per
// 4MiB XCD-L2); R9 static level-pair-per-XCD -> FETCH 1.26GB + load imbalance
// (2 tables = 8MB > 4MiB L2; coarse XCDs idle), 740us. Model correction: table
// REPLICATION across XCDs is cheap (~320MB of L2 fills, L3-served, ~15us); the
// only invariant that matters is <=1 table hot per XCD at any instant.
// Structure: 16 back-to-back launches, one level each (the empirically-fast 365us
// gather config from the original session), transpose fused via an 8MB ws:
//   even level l: gather -> ws[p] (float2, fully coalesced)
//   odd  level l: gather + read ws[p] -> one aligned float4 to out[p*8 + l/2]
// x and out use non-temporal hints so streams don't evict the resident table.
// Predicted: FETCH 0.45-0.65GB, WRITE ~320MB, aggregate ~350-430us.

static constexpr int NP = 1048576;
static constexpr int NL = 16;
static constexpr int TPB = 256;
static constexpr uint32_t HMASK = (1u << 19) - 1u;

typedef float f32x4 __attribute__((ext_vector_type(4)));

// res_i = floor(16 * b^i), b = f32(exp((ln512-ln16)/15)) = 1.2599210739135742
// Verified: absmax 2.4e-7 vs reference (R8/R9 runs).
__constant__ float c_res[NL] = {16.f, 20.f, 25.f, 32.f, 40.f, 50.f, 64.f, 80.f,
                                101.f, 128.f, 161.f, 203.f, 256.f, 322.f, 406.f, 512.f};

__device__ __forceinline__ float2 enc_one(
    float x0, float x1, float x2,
    float b0, float b1, float b2,
    float B0, float B1, float B2,
    const float2* __restrict__ tab, float res, float gate)
{
    // index path must be bit-exact vs numpy f32: sub/div/floor only
    float g0 = (B0 - b0) / res;
    float g1 = (B1 - b1) / res;
    float g2 = (B2 - b2) / res;
    float xc0 = fminf(fmaxf(x0, b0), B0);
    float xc1 = fminf(fmaxf(x1, b1), B1);
    float xc2 = fminf(fmaxf(x2, b2), B2);
    float f0 = floorf((xc0 - b0) / g0);
    float f1 = floorf((xc1 - b1) / g1);
    float f2 = floorf((xc2 - b2) / g2);
    // interpolation weights use RAW x (per reference)
    float v0 = f0 * g0 + b0;
    float v1 = f1 * g1 + b1;
    float v2 = f2 * g2 + b2;
    float w0 = (x0 - v0) / ((v0 + g0) - v0);
    float w1 = (x1 - v1) / ((v1 + g1) - v1);
    float w2 = (x2 - v2) / ((v2 + g2) - v2);

    uint32_t u0 = (uint32_t)(int)f0;
    uint32_t u1 = (uint32_t)(int)f1;
    uint32_t u2 = (uint32_t)(int)f2;
    uint32_t ya = u1 * 2654435761u, yb = (u1 + 1u) * 2654435761u;
    uint32_t za = u2 * 805459861u,  zb = (u2 + 1u) * 805459861u;
    uint32_t xa = u0, xb = u0 + 1u;

    // corner index = i*4 + j*2 + k (i on x, j on y, k on z)
    float2 e000 = tab[(xa ^ ya ^ za) & HMASK];
    float2 e001 = tab[(xa ^ ya ^ zb) & HMASK];
    float2 e010 = tab[(xa ^ yb ^ za) & HMASK];
    float2 e011 = tab[(xa ^ yb ^ zb) & HMASK];
    float2 e100 = tab[(xb ^ ya ^ za) & HMASK];
    float2 e101 = tab[(xb ^ ya ^ zb) & HMASK];
    float2 e110 = tab[(xb ^ yb ^ za) & HMASK];
    float2 e111 = tab[(xb ^ yb ^ zb) & HMASK];

    float s0 = 1.f - w0, s1 = 1.f - w1, s2 = 1.f - w2;
    float cx00x = e000.x * s0 + e100.x * w0, cx00y = e000.y * s0 + e100.y * w0;
    float cx01x = e001.x * s0 + e101.x * w0, cx01y = e001.y * s0 + e101.y * w0;
    float cx10x = e010.x * s0 + e110.x * w0, cx10y = e010.y * s0 + e110.y * w0;
    float cx11x = e011.x * s0 + e111.x * w0, cx11y = e011.y * s0 + e111.y * w0;
    float c0x = cx00x * s1 + cx10x * w1, c0y = cx00y * s1 + cx10y * w1;
    float c1x = cx01x * s1 + cx11x * w1, c1y = cx01y * s1 + cx11y * w1;
    float ox = c0x * s2 + c1x * w2;
    float oy = c0y * s2 + c1y * w2;
    return make_float2(ox * gate, oy * gate);
}

// One level per launch. Even level: stash float2 in ws (coalesced full lines).
// Odd level: gather + read stash -> one aligned float4 to out (2x sector amp,
// bounded 256MB total). Branch on (l&1) is launch-uniform.
__global__ __launch_bounds__(TPB) void k_lvl(
    const float* __restrict__ x, const float* __restrict__ emb,
    const float* __restrict__ lw, const float* __restrict__ bmin,
    const float* __restrict__ bmax, float2* __restrict__ ws,
    f32x4* __restrict__ out, int l)
{
    int p = blockIdx.x * TPB + threadIdx.x;

    // streamed: keep out of the way of the resident table in L2
    float x0 = __builtin_nontemporal_load(x + 3 * p + 0);
    float x1 = __builtin_nontemporal_load(x + 3 * p + 1);
    float x2 = __builtin_nontemporal_load(x + 3 * p + 2);
    float b0 = bmin[0], b1 = bmin[1], b2 = bmin[2];
    float B0 = bmax[0], B1 = bmax[1], B2 = bmax[2];

    float res = c_res[l];
    float gate = 1.0f / (1.0f + expf(-lw[l]));
    const float2* tab = (const float2*)(emb + ((size_t)l << 20));

    float2 r = enc_one(x0, x1, x2, b0, b1, b2, B0, B1, B2, tab, res, gate);

    if ((l & 1) == 0) {
        ws[p] = r;                       // coalesced 8B/lane, full lines
    } else {
        float2 a = ws[p];                // coalesced read of the stash
        f32x4 v = {a.x, a.y, r.x, r.y};  // levels (l-1, l)
        __builtin_nontemporal_store(v, &out[(size_t)p * 8 + (l >> 1)]);
    }
}

// Fallback (ws too small): R8 fused kernel — known-correct, 615us.
__global__ __launch_bounds__(TPB) void k_enc_fused(
    const float* __restrict__ x, const float* __restrict__ emb,
    const float* __restrict__ lw, const float* __restrict__ bmin,
    const float* __restrict__ bmax, f32x4* __restrict__ out)
{
    __shared__ float2 s[TPB][9];
    int t = threadIdx.x;
    size_t p0 = (size_t)blockIdx.x * TPB;
    int p = (int)p0 + t;

    float x0 = x[3 * p + 0], x1 = x[3 * p + 1], x2 = x[3 * p + 2];
    float b0 = bmin[0], b1 = bmin[1], b2 = bmin[2];
    float B0 = bmax[0], B1 = bmax[1], B2 = bmax[2];

#pragma unroll
    for (int ph = 0; ph < 2; ++ph) {
        if (ph) __syncthreads();
#pragma unroll
        for (int m = 0; m < 8; ++m) {
            int l = ph * 8 + m;
            float res = c_res[l];
            float gate = 1.0f / (1.0f + expf(-lw[l]));
            const float2* tab = (const float2*)(emb + ((size_t)l << 20));
            s[t][m] = enc_one(x0, x1, x2, b0, b1, b2, B0, B1, B2, tab, res, gate);
        }
        __syncthreads();
#pragma unroll
        for (int k = 0; k < 4; ++k) {
            int n = k * TPB + t;
            int q = n >> 2;
            int j = n & 3;
            float2 a = s[q][2 * j];
            float2 b = s[q][2 * j + 1];
            f32x4 v = {a.x, a.y, b.x, b.y};
            __builtin_nontemporal_store(v, &out[(p0 + (size_t)q) * 8 + ph * 4 + j]);
        }
    }
}

extern "C" void kernel_launch(void* const* d_in, const int* in_sizes, int n_in,
                              void* d_out, int out_size, void* d_ws, size_t ws_size,
                              hipStream_t stream) {
    const float* x    = (const float*)d_in[0];
    const float* emb  = (const float*)d_in[1];
    const float* lw   = (const float*)d_in[2];
    const float* bmin = (const float*)d_in[3];
    const float* bmax = (const float*)d_in[4];

    if (ws_size >= (size_t)NP * sizeof(float2)) {
        for (int l = 0; l < NL; ++l) {
            k_lvl<<<NP / TPB, TPB, 0, stream>>>(
                x, emb, lw, bmin, bmax, (float2*)d_ws, (f32x4*)d_out, l);
        }
    } else {
        k_enc_fused<<<NP / TPB, TPB, 0, stream>>>(
            x, emb, lw, bmin, bmax, (f32x4*)d_out);
    }
}